// Round 5
// baseline (79.967 us; speedup 1.0000x reference)
//
#include <hip/hip_runtime.h>
#include <math.h>

#define D 100
#define K 4
#define NREL 1000
#define CH 8
#define NT 256

// ws layout (32-bit words):
//   [0    , 1024) cnt
//   [1024 , 2049) start (NREL+1 used)
//   [3072 , 4096) cursor
//   [4096 , 8192) bucket (B <= 4096)
//   [8192 , ...) part[B*16] floats
#define WS_CNT    0
#define WS_START  1024
#define WS_CURSOR 3072
#define WS_BUCKET 4096
#define WS_PART   8192

__global__ void k_zero(int* ws) {
    ws[WS_CNT + blockIdx.x * 256 + threadIdx.x] = 0;
}

__global__ void k_hist(const int* __restrict__ rels, int B, int* ws) {
    int b = blockIdx.x * 256 + threadIdx.x;
    if (b < B) atomicAdd(&ws[WS_CNT + rels[b]], 1);
}

__global__ __launch_bounds__(1024) void k_scan(int* ws, int B) {
    __shared__ int sA[1024], sB[1024];
    const int tid = threadIdx.x;
    const int v = (tid < NREL) ? ws[WS_CNT + tid] : 0;
    sA[tid] = v;
    __syncthreads();
    int* src = sA; int* dst = sB;
    for (int off = 1; off < 1024; off <<= 1) {
        int x = src[tid];
        if (tid >= off) x += src[tid - off];
        dst[tid] = x;
        __syncthreads();
        int* t = src; src = dst; dst = t;
    }
    const int excl = src[tid] - v;
    if (tid < NREL) {
        ws[WS_START + tid]  = excl;
        ws[WS_CURSOR + tid] = excl;
    }
    if (tid == 0) ws[WS_START + NREL] = B;
}

__global__ void k_scatter(const int* __restrict__ rels, int B, int* ws) {
    int b = blockIdx.x * 256 + threadIdx.x;
    if (b < B) {
        int pos = atomicAdd(&ws[WS_CURSOR + rels[b]], 1);
        ws[WS_BUCKET + pos] = b;
    }
}

// One block per (relation, row-group of 25). Wave = tensor slice k.
// Reads its disjoint 10KB strip of W[r] once per <=8-item chunk with a fully
// unrolled 13-deep independent float4 load chain; writes per-(item,k,group)
// partials to distinct ws slots (bitwise deterministic).
__global__ __launch_bounds__(NT) void ntn_main(
    const int* __restrict__ heads, const int* __restrict__ tails,
    const float* __restrict__ E, const float* __restrict__ W,
    const float* __restrict__ V, const int* __restrict__ ws,
    float* __restrict__ part)
{
    const int r = blockIdx.x >> 2;
    const int g = blockIdx.x & 3;          // rows [g*25, g*25+25)
    const int cs = ws[WS_START + r];
    const int n  = ws[WS_START + r + 1] - cs;
    if (n <= 0) return;

    const int tid  = threadIdx.x;
    const int lane = tid & 63;
    const int k    = tid >> 6;
    const int dsub = lane / 25;            // 0/1 for lanes < 50
    const int c    = lane % 25;            // float4 column group
    const bool active = (lane < 50);

    __shared__ float e12[CH][2 * D];
    __shared__ float red[K][CH];
    __shared__ int   bb[CH];

    const float* Wk = W + ((size_t)r * K + k) * D * D + (size_t)g * 25 * D;
    const float* Vk = V + ((size_t)r * K + k) * 2 * D;
    const int* bucket = ws + WS_BUCKET;

    for (int base = 0; base < n; base += CH) {
        const int m = min(CH, n - base);
        if (tid < CH) bb[tid] = (tid < m) ? bucket[cs + base + tid] : -1;
        __syncthreads();
        for (int idx = tid; idx < CH * 2 * D; idx += NT) {
            const int it = idx / (2 * D), j = idx % (2 * D);
            float val = 0.f;
            const int b = bb[it];
            if (b >= 0) {
                const int ent = (j < D) ? heads[b] : tails[b];
                val = E[(size_t)ent * D + (j < D ? j : j - D)];
            }
            e12[it][j] = val;
        }
        __syncthreads();

        float4 e2r[CH];
        #pragma unroll
        for (int it = 0; it < CH; ++it)
            e2r[it] = active ? *(const float4*)&e12[it][D + c * 4]
                             : make_float4(0.f, 0.f, 0.f, 0.f);

        float acc[CH];
        #pragma unroll
        for (int it = 0; it < CH; ++it) acc[it] = 0.f;

        #pragma unroll
        for (int dp = 0; dp < 13; ++dp) {
            const int dd = dp * 2 + dsub;          // row within the 25-row group
            if (active && dd < 25) {
                const float4 wv = *(const float4*)&Wk[dd * D + c * 4];
                #pragma unroll
                for (int it = 0; it < CH; ++it) {
                    acc[it] += (wv.x * e2r[it].x + wv.y * e2r[it].y
                              + wv.z * e2r[it].z + wv.w * e2r[it].w)
                             * e12[it][g * 25 + dd];
                }
            }
        }
        if (g == 0) {   // g_a: v[r,k,:].[e1;e2] folded into group-0 partial
            for (int j = lane; j < 2 * D; j += 64) {
                const float vv = Vk[j];
                #pragma unroll
                for (int it = 0; it < CH; ++it) acc[it] += vv * e12[it][j];
            }
        }
        #pragma unroll
        for (int it = 0; it < CH; ++it) {
            float s = acc[it];
            #pragma unroll
            for (int off = 32; off > 0; off >>= 1) s += __shfl_down(s, off, 64);
            if (lane == 0) red[k][it] = s;
        }
        __syncthreads();
        if (tid < K * CH) {
            const int kk = tid >> 3, it = tid & 7;
            if (it < m)
                part[(size_t)bb[it] * 16 + kk * 4 + g] = red[kk][it];
        }
        __syncthreads();
    }
}

__global__ __launch_bounds__(256) void ntn_epilogue(
    const float* __restrict__ part, const int* __restrict__ rels,
    const float* __restrict__ Bp, const float* __restrict__ U,
    float* __restrict__ out, int B)
{
    const int b = blockIdx.x * 256 + threadIdx.x;
    if (b >= B) return;
    const int r = rels[b];
    const float4* p4 = (const float4*)&part[(size_t)b * 16];
    float score = 0.f;
    #pragma unroll
    for (int k = 0; k < K; ++k) {
        const float4 p = p4[k];
        const float gsum = (p.x + p.y) + (p.z + p.w) + Bp[r * K + k];
        score += U[r * K + k] * tanhf(gsum);
    }
    out[b] = 1.f / (1.f + expf(-score));
}

extern "C" void kernel_launch(void* const* d_in, const int* in_sizes, int n_in,
                              void* d_out, int out_size, void* d_ws, size_t ws_size,
                              hipStream_t stream) {
    const int*   heads = (const int*)d_in[0];
    const int*   tails = (const int*)d_in[1];
    const int*   rels  = (const int*)d_in[2];
    const float* E     = (const float*)d_in[3];
    const float* W     = (const float*)d_in[4];
    const float* V     = (const float*)d_in[5];
    const float* Bp    = (const float*)d_in[6];
    const float* U     = (const float*)d_in[7];
    float* out = (float*)d_out;

    const int B = in_sizes[0];
    int*   ws   = (int*)d_ws;
    float* part = (float*)d_ws + WS_PART;

    k_zero<<<4, 256, 0, stream>>>(ws);
    k_hist<<<(B + 255) / 256, 256, 0, stream>>>(rels, B, ws);
    k_scan<<<1, 1024, 0, stream>>>(ws, B);
    k_scatter<<<(B + 255) / 256, 256, 0, stream>>>(rels, B, ws);
    ntn_main<<<NREL * 4, NT, 0, stream>>>(heads, tails, E, W, V, ws, part);
    ntn_epilogue<<<(B + 255) / 256, 256, 0, stream>>>(part, rels, Bp, U, out, B);
}

// Round 6
// 74.187 us; speedup vs baseline: 1.0779x; 1.0779x over previous
//
#include <hip/hip_runtime.h>
#include <math.h>

#define D 100
#define K 4
#define NREL 1000
#define CH 8
#define NT 256

// ws layout (32-bit words):
//   [0    , 1024) cnt
//   [1024 , 3072) start (NREL+1 used)
//   [3072 , 4096) cursor
//   [4096 , 8192) bucket (B <= 4096)
//   [8192 , ...)  part[B*8] floats (b*8 + k*2 + g), each written exactly once
#define WS_CNT    0
#define WS_START  1024
#define WS_CURSOR 3072
#define WS_BUCKET 4096
#define WS_PART   8192

__global__ void k_zero(int* ws) {
    ws[WS_CNT + blockIdx.x * 256 + threadIdx.x] = 0;
}

__global__ void k_hist(const int* __restrict__ rels, int B, int* ws) {
    int b = blockIdx.x * 256 + threadIdx.x;
    if (b < B) atomicAdd(&ws[WS_CNT + rels[b]], 1);
}

__global__ __launch_bounds__(1024) void k_scan(int* ws, int B) {
    __shared__ int sA[1024], sB[1024];
    const int tid = threadIdx.x;
    const int v = (tid < NREL) ? ws[WS_CNT + tid] : 0;
    sA[tid] = v;
    __syncthreads();
    int* src = sA; int* dst = sB;
    for (int off = 1; off < 1024; off <<= 1) {
        int x = src[tid];
        if (tid >= off) x += src[tid - off];
        dst[tid] = x;
        __syncthreads();
        int* t = src; src = dst; dst = t;
    }
    const int excl = src[tid] - v;
    if (tid < NREL) {
        ws[WS_START + tid]  = excl;
        ws[WS_CURSOR + tid] = excl;
    }
    if (tid == 0) ws[WS_START + NREL] = B;
}

__global__ void k_scatter(const int* __restrict__ rels, int B, int* ws) {
    int b = blockIdx.x * 256 + threadIdx.x;
    if (b < B) {
        int pos = atomicAdd(&ws[WS_CURSOR + rels[b]], 1);
        ws[WS_BUCKET + pos] = b;
    }
}

// One block per (relation, row-half). Wave = tensor slice k. Streams its
// disjoint 20KB strip of W[r] once per <=8-item chunk as a FULLY UNROLLED
// 25-step float4 chain (launch_bounds(,2) -> VGPR cap 128 so the compiler
// keeps many loads in flight). Writes per-(item,k,half) partials to distinct
// ws slots -> bitwise deterministic regardless of bucket order.
__global__ __launch_bounds__(NT, 2) void ntn_main(
    const int* __restrict__ heads, const int* __restrict__ tails,
    const float* __restrict__ E, const float* __restrict__ W,
    const float* __restrict__ V, const int* __restrict__ ws,
    float* __restrict__ part)
{
    const int r = blockIdx.x >> 1;
    const int g = blockIdx.x & 1;          // rows [g*50, g*50+50)
    const int cs = ws[WS_START + r];
    const int n  = ws[WS_START + r + 1] - cs;
    if (n <= 0) return;

    const int tid  = threadIdx.x;
    const int lane = tid & 63;
    const int k    = tid >> 6;             // wave id == tensor slice
    const int dsub = lane / 25;            // 0/1 for lanes < 50
    const int c    = lane % 25;            // float4 column group
    const bool active = (lane < 50);

    __shared__ float e12[CH][2 * D];
    __shared__ float red[K][CH];
    __shared__ int   bb[CH];

    const float*  Wg = W + ((size_t)r * K + k) * D * D + (size_t)g * 50 * D;
    const float*  Vk = V + ((size_t)r * K + k) * 2 * D;
    const float4* E4 = reinterpret_cast<const float4*>(E);   // 25 float4 per row
    const int* bucket = ws + WS_BUCKET;

    for (int base = 0; base < n; base += CH) {
        const int m = min(CH, n - base);
        __syncthreads();   // previous chunk fully consumed before overwrite
        if (tid < CH) bb[tid] = (tid < m) ? bucket[cs + base + tid] : -1;
        __syncthreads();

        // Wave-cooperative gather: wave k loads items {k, k+4}; lane = (q=e1/e2, col group).
        if (active) {
            const int b0 = bb[k], b1 = bb[k + 4];
            float4 z = make_float4(0.f, 0.f, 0.f, 0.f);
            float4 v0 = z, v1 = z;
            if (b0 >= 0) {
                const int e0 = dsub ? tails[b0] : heads[b0];
                v0 = E4[(size_t)e0 * 25 + c];
            }
            if (b1 >= 0) {
                const int e1 = dsub ? tails[b1] : heads[b1];
                v1 = E4[(size_t)e1 * 25 + c];
            }
            *(float4*)&e12[k][dsub * D + c * 4]     = v0;
            *(float4*)&e12[k + 4][dsub * D + c * 4] = v1;
        }
        __syncthreads();

        float4 e2r[CH];
        #pragma unroll
        for (int it = 0; it < CH; ++it)
            e2r[it] = active ? *(const float4*)&e12[it][D + c * 4]
                             : make_float4(0.f, 0.f, 0.f, 0.f);

        float acc[CH];
        #pragma unroll
        for (int it = 0; it < CH; ++it) acc[it] = 0.f;

        if (active) {
            #pragma unroll   // 25 static, independent float4 loads -> deep in flight
            for (int dp = 0; dp < 25; ++dp) {
                const int dd = dp * 2 + dsub;          // row within the 50-row group
                const float4 wv = *(const float4*)&Wg[dd * D + c * 4];
                const int drow = g * 50 + dd;
                #pragma unroll
                for (int it = 0; it < CH; ++it) {
                    acc[it] += (wv.x * e2r[it].x + wv.y * e2r[it].y
                              + wv.z * e2r[it].z + wv.w * e2r[it].w)
                             * e12[it][drow];
                }
            }
        }
        if (g == 0) {   // g_a: v[r,k,:].[e1;e2] folded into half-0 partial
            for (int j = lane; j < 2 * D; j += 64) {
                const float vv = Vk[j];
                #pragma unroll
                for (int it = 0; it < CH; ++it) acc[it] += vv * e12[it][j];
            }
        }
        #pragma unroll
        for (int it = 0; it < CH; ++it) {
            float s = acc[it];
            #pragma unroll
            for (int off = 32; off > 0; off >>= 1) s += __shfl_down(s, off, 64);
            if (lane == 0) red[k][it] = s;
        }
        __syncthreads();
        if (tid < K * CH) {
            const int kk = tid >> 3, it = tid & 7;
            if (it < m)
                part[(size_t)bb[it] * 8 + kk * 2 + g] = red[kk][it];
        }
    }
}

__global__ __launch_bounds__(256) void ntn_epilogue(
    const float* __restrict__ part, const int* __restrict__ rels,
    const float* __restrict__ Bp, const float* __restrict__ U,
    float* __restrict__ out, int B)
{
    const int b = blockIdx.x * 256 + threadIdx.x;
    if (b >= B) return;
    const int r = rels[b];
    const float4* p4 = (const float4*)&part[(size_t)b * 8];
    const float4 pa = p4[0];   // k0g0 k0g1 k1g0 k1g1
    const float4 pb = p4[1];   // k2g0 k2g1 k3g0 k3g1
    float score = 0.f;
    score += U[r * K + 0] * tanhf(pa.x + pa.y + Bp[r * K + 0]);
    score += U[r * K + 1] * tanhf(pa.z + pa.w + Bp[r * K + 1]);
    score += U[r * K + 2] * tanhf(pb.x + pb.y + Bp[r * K + 2]);
    score += U[r * K + 3] * tanhf(pb.z + pb.w + Bp[r * K + 3]);
    out[b] = 1.f / (1.f + expf(-score));
}

extern "C" void kernel_launch(void* const* d_in, const int* in_sizes, int n_in,
                              void* d_out, int out_size, void* d_ws, size_t ws_size,
                              hipStream_t stream) {
    const int*   heads = (const int*)d_in[0];
    const int*   tails = (const int*)d_in[1];
    const int*   rels  = (const int*)d_in[2];
    const float* E     = (const float*)d_in[3];
    const float* W     = (const float*)d_in[4];
    const float* V     = (const float*)d_in[5];
    const float* Bp    = (const float*)d_in[6];
    const float* U     = (const float*)d_in[7];
    float* out = (float*)d_out;

    const int B = in_sizes[0];
    int*   ws   = (int*)d_ws;
    float* part = (float*)d_ws + WS_PART;

    k_zero<<<4, 256, 0, stream>>>(ws);
    k_hist<<<(B + 255) / 256, 256, 0, stream>>>(rels, B, ws);
    k_scan<<<1, 1024, 0, stream>>>(ws, B);
    k_scatter<<<(B + 255) / 256, 256, 0, stream>>>(rels, B, ws);
    ntn_main<<<NREL * 2, NT, 0, stream>>>(heads, tails, E, W, V, ws, part);
    ntn_epilogue<<<(B + 255) / 256, 256, 0, stream>>>(part, rels, Bp, U, out, B);
}

// Round 7
// 68.753 us; speedup vs baseline: 1.1631x; 1.0790x over previous
//
#include <hip/hip_runtime.h>
#include <math.h>

#define D 100
#define K 4
#define NREL 1000
#define CH 8
#define NT 512

// --- Grouping: one 1024-thread block. LDS histogram -> LDS scan -> scatter.
// Emits start[NREL+1] and, per bucket slot, the batch index AND pre-gathered
// head/tail entity ids (shortens the main kernel's dependent load chain).
__global__ __launch_bounds__(1024) void k_group(
    const int* __restrict__ rels, const int* __restrict__ heads,
    const int* __restrict__ tails, int B,
    int* __restrict__ start, int* __restrict__ bb,
    int* __restrict__ bh, int* __restrict__ bt)
{
    __shared__ int sA[1024], sB[1024];
    const int tid = threadIdx.x;
    sA[tid] = 0;
    __syncthreads();
    for (int b = tid; b < B; b += 1024) atomicAdd(&sA[rels[b]], 1);
    __syncthreads();
    const int v = sA[tid];
    int* src = sA; int* dst = sB;
    for (int off = 1; off < 1024; off <<= 1) {
        int x = src[tid];
        if (tid >= off) x += src[tid - off];
        dst[tid] = x;
        __syncthreads();
        int* t = src; src = dst; dst = t;
    }
    const int excl = src[tid] - v;     // exclusive scan
    if (tid < NREL) start[tid] = excl;
    if (tid == 0)   start[NREL] = B;
    int* cur = dst;                    // free buffer -> cursors
    cur[tid] = excl;
    __syncthreads();
    for (int b = tid; b < B; b += 1024) {
        const int r = rels[b];
        const int pos = atomicAdd(&cur[r], 1);
        bb[pos] = b;
        bh[pos] = heads[b];
        bt[pos] = tails[b];
    }
}

// One block per relation: 8 waves = (slice k 0..3) x (row-half g 0..1).
// Streams W[r] exactly once per <=8-item chunk; 5 named float4 loads in
// flight per lane (fits 128 VGPR, no spill); epilogue fused in-block.
// Every out[b] computed in a fixed arithmetic order -> bitwise deterministic
// regardless of bucket scatter order.
#define WLOAD(u) const float4 wv##u = Wg4[(bat10 + (u)*2 + dsub) * 25 + c];
#define WFMA(u) { \
    const int drow = gbase + bat10 + (u)*2 + dsub; \
    _Pragma("unroll") \
    for (int it = 0; it < CH; ++it) { \
        acc[it] += (wv##u.x * e2r[it].x + wv##u.y * e2r[it].y \
                  + wv##u.z * e2r[it].z + wv##u.w * e2r[it].w) * e12[it][drow]; \
    } }

__global__ __launch_bounds__(NT, 4) void ntn_main(
    const float* __restrict__ E, const float* __restrict__ W,
    const float* __restrict__ V, const float* __restrict__ Bp,
    const float* __restrict__ U, const int* __restrict__ start,
    const int* __restrict__ bb, const int* __restrict__ bh,
    const int* __restrict__ bt, float* __restrict__ out)
{
    const int r  = blockIdx.x;
    const int cs = start[r];
    const int n  = start[r + 1] - cs;
    if (n <= 0) return;

    const int tid  = threadIdx.x;
    const int lane = tid & 63;
    const int w    = tid >> 6;       // 0..7
    const int k    = w & 3;          // tensor slice
    const int g    = w >> 2;         // row half
    const int dsub = lane / 25;      // 0/1 for lanes < 50
    const int c    = lane % 25;      // float4 column group
    const bool active = (lane < 50);
    const int gbase = g * 50;

    __shared__ float e12[CH][2 * D];
    __shared__ float red[8][CH];
    __shared__ int   ob[CH];

    const float4* Wg4 = reinterpret_cast<const float4*>(
        W + ((size_t)r * K + k) * D * D + (size_t)gbase * D);
    const float*  Vk  = V + ((size_t)r * K + k) * 2 * D;
    const float4* E4  = reinterpret_cast<const float4*>(E);

    for (int base = 0; base < n; base += CH) {
        const int m = min(CH, n - base);
        __syncthreads();   // previous chunk fully consumed before overwrite
        if (tid < m) ob[tid] = bb[cs + base + tid];
        // wave w gathers item w (head row -> e12[w][0:100), tail -> [100:200))
        if (active && w < m) {
            const int idx = cs + base + w;                 // wave-uniform
            const int ent = dsub ? bt[idx] : bh[idx];
            *(float4*)&e12[w][dsub * D + c * 4] = E4[(size_t)ent * 25 + c];
        }
        __syncthreads();

        float4 e2r[CH];
        #pragma unroll
        for (int it = 0; it < CH; ++it)
            e2r[it] = *(const float4*)&e12[it][D + c * 4];

        float acc[CH];
        #pragma unroll
        for (int it = 0; it < CH; ++it) acc[it] = 0.f;

        if (active) {
            #pragma unroll 1   // keep 5 loads in flight, NOT 25 (VGPR budget)
            for (int bat = 0; bat < 5; ++bat) {
                const int bat10 = bat * 10;
                WLOAD(0) WLOAD(1) WLOAD(2) WLOAD(3) WLOAD(4)
                WFMA(0) WFMA(1) WFMA(2) WFMA(3) WFMA(4)
            }
        }
        if (g == 0) {   // g_a: v[r,k,:].[e1;e2], folded into half-0 partial
            for (int j = lane; j < 2 * D; j += 64) {
                const float vv = Vk[j];
                #pragma unroll
                for (int it = 0; it < CH; ++it) acc[it] += vv * e12[it][j];
            }
        }
        #pragma unroll
        for (int it = 0; it < CH; ++it) {
            float s = acc[it];
            #pragma unroll
            for (int off = 32; off > 0; off >>= 1) s += __shfl_down(s, off, 64);
            if (lane == 0) red[w][it] = s;
        }
        __syncthreads();
        if (tid < m) {   // fused epilogue: all partials are block-local
            const int rb = r * K;
            float score = 0.f;
            #pragma unroll
            for (int kk = 0; kk < K; ++kk) {
                const float gv = red[kk][tid] + red[kk + 4][tid] + Bp[rb + kk];
                score += U[rb + kk] * tanhf(gv);
            }
            out[ob[tid]] = 1.f / (1.f + expf(-score));
        }
    }
}

extern "C" void kernel_launch(void* const* d_in, const int* in_sizes, int n_in,
                              void* d_out, int out_size, void* d_ws, size_t ws_size,
                              hipStream_t stream) {
    const int*   heads = (const int*)d_in[0];
    const int*   tails = (const int*)d_in[1];
    const int*   rels  = (const int*)d_in[2];
    const float* E     = (const float*)d_in[3];
    const float* W     = (const float*)d_in[4];
    const float* V     = (const float*)d_in[5];
    const float* Bp    = (const float*)d_in[6];
    const float* U     = (const float*)d_in[7];
    float* out = (float*)d_out;

    const int B = in_sizes[0];
    int* start = (int*)d_ws;           // [NREL+1]
    int* bb    = start + 1024;         // [B]
    int* bh    = bb + B;               // [B]
    int* bt    = bh + B;               // [B]

    k_group<<<1, 1024, 0, stream>>>(rels, heads, tails, B, start, bb, bh, bt);
    ntn_main<<<NREL, NT, 0, stream>>>(E, W, V, Bp, U, start, bb, bh, bt, out);
}